// Round 6
// baseline (264.968 us; speedup 1.0000x reference)
//
#include <hip/hip_runtime.h>
#include <hip/hip_fp16.h>

#define BZ    167              // grid3d_index dims 0/1 (SIZE + 2*MARGIN)
#define BZ2   83               // BZ/2
#define NX    84               // BZ/2 + 1  (last axis)
#define NCELL (BZ * BZ * NX)   // 2,342,676 cells
#define NBX   51               // ceil(13041/256) blocks/batch (fallback tiers)
#define NBX2  102              // ceil(13041/128) blocks/batch (half-lane kernel)

// ---- conversion helpers ----
static __device__ __forceinline__ unsigned f2h2u(float a, float b) {
    __half2 h = __floats2half2_rn(a, b);
    return __builtin_bit_cast(unsigned, h);
}
static __device__ __forceinline__ __half2 u2h2(unsigned u) {
    return __builtin_bit_cast(__half2, u);
}
// bf16 helpers (fallback tier 2)
static __device__ __forceinline__ unsigned f2bf(float f) {
    unsigned u = __float_as_uint(f);
    return (u + 0x7FFFu + ((u >> 16) & 1u)) >> 16;
}
static __device__ __forceinline__ float bf_lo(unsigned u) {
    return __uint_as_float(u << 16);
}
static __device__ __forceinline__ float bf_hi(unsigned u) {
    return __uint_as_float(u & 0xFFFF0000u);
}

// ---- fused pre-pass: pack weights fp32->f16 (coalesced float4->uint2) AND
// build garr[cell] = (j, bias_f16x2) in one dispatch ----
__global__ __launch_bounds__(256) void pack_all(
    const float4* __restrict__ wsrc, uint2* __restrict__ wdst, int nw4, int nbw,
    const int* __restrict__ grid, const float* __restrict__ bias,
    int2* __restrict__ garr, int ncell)
{
    if ((int)blockIdx.x < nbw) {
        const int i = blockIdx.x * 256 + threadIdx.x;
        if (i >= nw4) return;
        const float4 v = wsrc[i];
        wdst[i] = make_uint2(f2h2u(v.x, v.y), f2h2u(v.z, v.w));
    } else {
        const int i = ((int)blockIdx.x - nbw) * 256 + threadIdx.x;
        if (i >= ncell) return;
        const int j = grid[i];
        unsigned bb = 0u;
        if (j >= 0)
            bb = f2h2u(bias[2 * j], bias[2 * j + 1]);
        garr[i] = make_int2(j, (int)bb);
    }
}

// ============== main kernel: lane-paired f16 packed-math gathers =============
// Lane pair (2q,2q+1) = one point: even lane handles input dims 0-3 + first
// 16B of each weight record, odd lane dims 4-7 + second 16B. One dwordx4 per
// corner covers 32 full records (each record's lines touched once). The 16B
// payload is 4 half2 = (w_k_c0, w_k_c1) pairs -> pure v_pk_fma_f16 math, no
// unpack instructions. Partials combine via shfl_xor(1); 4B/lane store.
__global__ __launch_bounds__(256) void svr_h16(
    const float*    __restrict__ input,   // (B, 8)
    const unsigned* __restrict__ wpk,     // (W, 8) uints = 16 f16
    const int2*     __restrict__ garr,    // (NCELL): (j, bias f16x2)
    const float*    __restrict__ rot,     // (B, 3, 3)
    const float*    __restrict__ coord,   // (P, 2)
    const int*      __restrict__ max_r,
    float*          __restrict__ out,     // (B, P, 2)
    int P)
{
    const int m    = blockIdx.x;
    const int xcd  = m & 7;                    // XCD-aware batch striping
    const int slot = m >> 3;
    const int b    = (slot / NBX2) * 8 + xcd;
    const int lane = threadIdx.x;
    const int half = lane & 1;
    const int p    = (slot % NBX2) * 128 + (lane >> 1);
    if (p >= P) return;

    const float2 xy = *(const float2*)(coord + 2 * p);
    const float x = xy.x, y = xy.y;

    const int mr = min(max_r[0], (BZ - 6) / 2);
    const bool valid = (x * x + y * y) <= (float)(mr * mr);

    float* o = out + (((size_t)b * P + p) * 2 + half);   // 4B/lane, coalesced
    if (!valid) {
        *o = 0.f;
        return;
    }

    const float* R = rot + b * 9;
    float cx = fmaf(R[1], y, R[0] * x);
    float cy = fmaf(R[4], y, R[3] * x);
    float cz = fmaf(R[7], y, R[6] * x);

    float sgn = 1.f;
    if (cx < 0.f) { cx = -cx; cy = -cy; cz = -cz; sgn = -1.f; }

    const float fx = floorf(cx), fy = floorf(cy), fz = floorf(cz);
    const float tx = cx - fx, ty = cy - fy, tz = cz - fz;
    const int ix = (int)fx;
    const int iy = (int)fy + BZ2;
    const int iz = (int)fz + BZ2;

    // this lane's half of input[b], broadcast into half2 per dim
    const float4 ihf = *(const float4*)(input + b * 8 + half * 4);
    const __half2 ih0 = __float2half2_rn(ihf.x);
    const __half2 ih1 = __float2half2_rn(ihf.y);
    const __half2 ih2 = __float2half2_rn(ihf.z);
    const __half2 ih3 = __float2half2_rn(ihf.w);

    // clustered (j,bias) loads — lane pairs share addresses (coalesce), few
    // lines per instruction
    int2 G[8];
    #pragma unroll
    for (int dz = 0; dz < 2; ++dz) {
        #pragma unroll
        for (int dy = 0; dy < 2; ++dy) {
            const int base = ((iz + dz) * BZ + (iy + dy)) * NX + ix;
            const int c = dz * 4 + dy * 2;
            G[c + 0] = garr[base + 0];
            G[c + 1] = garr[base + 1];
        }
    }

    int     jj[8];
    __half2 wch[8];
    {
        const float wx0 = 1.f - tx, wy0 = 1.f - ty, wz0 = 1.f - tz;
        #pragma unroll
        for (int c = 0; c < 8; ++c) {
            const int dx = c & 1, dy = (c >> 1) & 1, dz = c >> 2;
            const float w = (dx ? tx : wx0) * (dy ? ty : wy0) * (dz ? tz : wz0);
            const int j = G[c].x;
            wch[c] = __float2half2_rn((j >= 0) ? w : 0.f);
            jj[c] = max(j, 0);
        }
    }

    // one 16B scatter load per corner per lane = full 32B record per lane pair
    uint4 U[8];
    #pragma unroll
    for (int c = 0; c < 8; ++c)
        U[c] = *(const uint4*)(wpk + (size_t)jj[c] * 8 + half * 4);

    const __half2 z2 = __float2half2_rn(0.f);
    __half2 acc01 = z2;
    #pragma unroll
    for (int c = 0; c < 8; ++c) {
        // bias contributes once per point: even lane seeds with it
        __half2 v01 = half ? z2 : u2h2((unsigned)G[c].y);
        v01 = __hfma2(ih0, u2h2(U[c].x), v01);
        v01 = __hfma2(ih1, u2h2(U[c].y), v01);
        v01 = __hfma2(ih2, u2h2(U[c].z), v01);
        v01 = __hfma2(ih3, u2h2(U[c].w), v01);
        acc01 = __hfma2(wch[c], v01, acc01);
    }

    // combine the two half-dot partials within the lane pair (f32)
    const float a0 = __low2float(acc01);
    const float a1 = __high2float(acc01);
    const float t0 = a0 + __shfl_xor(a0, 1);
    const float t1 = (a1 + __shfl_xor(a1, 1)) * sgn;
    *o = half ? t1 : t0;
}

// ============ fallback tier 2: bf16 weights + separate bias ==================
__global__ __launch_bounds__(256) void pack_w(
    const float4* __restrict__ src, uint2* __restrict__ dst, int n)
{
    const int i = blockIdx.x * 256 + threadIdx.x;
    if (i >= n) return;
    const float4 v = src[i];
    dst[i] = make_uint2(f2bf(v.x) | (f2bf(v.y) << 16),
                        f2bf(v.z) | (f2bf(v.w) << 16));
}
__global__ __launch_bounds__(256) void pack_b(
    const float* __restrict__ bias, unsigned* __restrict__ bpk, int W)
{
    const int j = blockIdx.x * 256 + threadIdx.x;
    if (j >= W) return;
    bpk[j] = f2bf(bias[2 * j]) | (f2bf(bias[2 * j + 1]) << 16);
}

__global__ __launch_bounds__(256) void svr_bf16(
    const float* __restrict__ input, const unsigned* __restrict__ wpk,
    const unsigned* __restrict__ bpk, const int* __restrict__ grid3d,
    const float* __restrict__ rot, const float* __restrict__ coord,
    const int* __restrict__ max_r, float* __restrict__ out, int P)
{
    const int m    = blockIdx.x;
    const int xcd  = m & 7;
    const int slot = m >> 3;
    const int b    = (slot / NBX) * 8 + xcd;
    const int p    = (slot % NBX) * 256 + threadIdx.x;
    if (p >= P) return;

    const float x = coord[2 * p + 0];
    const float y = coord[2 * p + 1];
    const int mr = min(max_r[0], (BZ - 6) / 2);
    const bool valid = (x * x + y * y) <= (float)(mr * mr);
    float2* o = (float2*)(out + ((size_t)b * P + p) * 2);
    if (!valid) { *o = make_float2(0.f, 0.f); return; }

    const float* R = rot + b * 9;
    float cx = fmaf(R[1], y, R[0] * x);
    float cy = fmaf(R[4], y, R[3] * x);
    float cz = fmaf(R[7], y, R[6] * x);
    float sgn = 1.f;
    if (cx < 0.f) { cx = -cx; cy = -cy; cz = -cz; sgn = -1.f; }
    const float fx = floorf(cx), fy = floorf(cy), fz = floorf(cz);
    const float tx = cx - fx, ty = cy - fy, tz = cz - fz;
    const int ix = (int)fx, iy = (int)fy + BZ2, iz = (int)fz + BZ2;

    const float* ib = input + b * 8;
    const float in0 = ib[0], in1 = ib[1], in2 = ib[2], in3 = ib[3];
    const float in4 = ib[4], in5 = ib[5], in6 = ib[6], in7 = ib[7];

    int jj[8]; float wc[8];
    const float wx0 = 1.f - tx, wy0 = 1.f - ty, wz0 = 1.f - tz;
    #pragma unroll
    for (int dz = 0; dz < 2; ++dz)
        #pragma unroll
        for (int dy = 0; dy < 2; ++dy) {
            const int base = ((iz + dz) * BZ + (iy + dy)) * NX + ix;
            #pragma unroll
            for (int dx = 0; dx < 2; ++dx) {
                const int c = dz * 4 + dy * 2 + dx;
                const int j = grid3d[base + dx];
                const float w = (dx ? tx : wx0) * (dy ? ty : wy0) * (dz ? tz : wz0);
                wc[c] = (j >= 0) ? w : 0.f;
                jj[c] = max(j, 0);
            }
        }

    uint4 U0[8], U1[8]; unsigned BB[8];
    #pragma unroll
    for (int c = 0; c < 8; ++c) {
        const uint4* wp = (const uint4*)(wpk + (size_t)jj[c] * 8);
        U0[c] = wp[0]; U1[c] = wp[1]; BB[c] = bpk[jj[c]];
    }

    float acc0 = 0.f, acc1 = 0.f;
    #pragma unroll
    for (int c = 0; c < 8; ++c) {
        const float w = wc[c];
        float v0 = bf_lo(BB[c]), v1 = bf_hi(BB[c]);
        v0 = fmaf(in0, bf_lo(U0[c].x), v0); v1 = fmaf(in0, bf_hi(U0[c].x), v1);
        v0 = fmaf(in1, bf_lo(U0[c].y), v0); v1 = fmaf(in1, bf_hi(U0[c].y), v1);
        v0 = fmaf(in2, bf_lo(U0[c].z), v0); v1 = fmaf(in2, bf_hi(U0[c].z), v1);
        v0 = fmaf(in3, bf_lo(U0[c].w), v0); v1 = fmaf(in3, bf_hi(U0[c].w), v1);
        v0 = fmaf(in4, bf_lo(U1[c].x), v0); v1 = fmaf(in4, bf_hi(U1[c].x), v1);
        v0 = fmaf(in5, bf_lo(U1[c].y), v0); v1 = fmaf(in5, bf_hi(U1[c].y), v1);
        v0 = fmaf(in6, bf_lo(U1[c].z), v0); v1 = fmaf(in6, bf_hi(U1[c].z), v1);
        v0 = fmaf(in7, bf_lo(U1[c].w), v0); v1 = fmaf(in7, bf_hi(U1[c].w), v1);
        acc0 = fmaf(w, v0, acc0);
        acc1 = fmaf(w, v1, acc1);
    }
    *o = make_float2(acc0, acc1 * sgn);
}

// ============ fallback tier 3: direct fp32 (no workspace needed) =============
__global__ __launch_bounds__(256) void svr_fp32(
    const float* __restrict__ input, const float* __restrict__ weight,
    const float* __restrict__ bias, const int* __restrict__ grid3d,
    const float* __restrict__ rot, const float* __restrict__ coord,
    const int* __restrict__ max_r, float* __restrict__ out, int P)
{
    const int m    = blockIdx.x;
    const int xcd  = m & 7;
    const int slot = m >> 3;
    const int b    = (slot / NBX) * 8 + xcd;
    const int p    = (slot % NBX) * 256 + threadIdx.x;
    if (p >= P) return;

    const float x = coord[2 * p + 0];
    const float y = coord[2 * p + 1];
    const int mr = min(max_r[0], (BZ - 6) / 2);
    const bool valid = (x * x + y * y) <= (float)(mr * mr);
    float2* o = (float2*)(out + ((size_t)b * P + p) * 2);
    if (!valid) { *o = make_float2(0.f, 0.f); return; }

    const float* R = rot + b * 9;
    float cx = fmaf(R[1], y, R[0] * x);
    float cy = fmaf(R[4], y, R[3] * x);
    float cz = fmaf(R[7], y, R[6] * x);
    float sgn = 1.f;
    if (cx < 0.f) { cx = -cx; cy = -cy; cz = -cz; sgn = -1.f; }
    const float fx = floorf(cx), fy = floorf(cy), fz = floorf(cz);
    const float tx = cx - fx, ty = cy - fy, tz = cz - fz;
    const int ix = (int)fx, iy = (int)fy + BZ2, iz = (int)fz + BZ2;

    const float* ib = input + b * 8;
    const float in0 = ib[0], in1 = ib[1], in2 = ib[2], in3 = ib[3];
    const float in4 = ib[4], in5 = ib[5], in6 = ib[6], in7 = ib[7];

    int jj[8]; float wc[8];
    const float wx0 = 1.f - tx, wy0 = 1.f - ty, wz0 = 1.f - tz;
    #pragma unroll
    for (int dz = 0; dz < 2; ++dz)
        #pragma unroll
        for (int dy = 0; dy < 2; ++dy) {
            const int base = ((iz + dz) * BZ + (iy + dy)) * NX + ix;
            #pragma unroll
            for (int dx = 0; dx < 2; ++dx) {
                const int c = dz * 4 + dy * 2 + dx;
                const int j = grid3d[base + dx];
                const float w = (dx ? tx : wx0) * (dy ? ty : wy0) * (dz ? tz : wz0);
                wc[c] = (j >= 0) ? w : 0.f;
                jj[c] = max(j, 0);
            }
        }

    float acc0 = 0.f, acc1 = 0.f;
    #pragma unroll
    for (int c = 0; c < 8; ++c) {
        const size_t j = (size_t)jj[c];
        const float4* wp = (const float4*)(weight + j * 16);
        const float4 W0 = wp[0], W1 = wp[1], W2 = wp[2], W3 = wp[3];
        const float2 bb = *(const float2*)(bias + j * 2);
        const float w = wc[c];
        float v0 = bb.x, v1 = bb.y;
        v0 = fmaf(in0, W0.x, v0); v1 = fmaf(in0, W0.y, v1);
        v0 = fmaf(in1, W0.z, v0); v1 = fmaf(in1, W0.w, v1);
        v0 = fmaf(in2, W1.x, v0); v1 = fmaf(in2, W1.y, v1);
        v0 = fmaf(in3, W1.z, v0); v1 = fmaf(in3, W1.w, v1);
        v0 = fmaf(in4, W2.x, v0); v1 = fmaf(in4, W2.y, v1);
        v0 = fmaf(in5, W2.z, v0); v1 = fmaf(in5, W2.w, v1);
        v0 = fmaf(in6, W3.x, v0); v1 = fmaf(in6, W3.y, v1);
        v0 = fmaf(in7, W3.z, v0); v1 = fmaf(in7, W3.w, v1);
        acc0 = fmaf(w, v0, acc0);
        acc1 = fmaf(w, v1, acc1);
    }
    *o = make_float2(acc0, acc1 * sgn);
}

extern "C" void kernel_launch(void* const* d_in, const int* in_sizes, int n_in,
                              void* d_out, int out_size, void* d_ws, size_t ws_size,
                              hipStream_t stream) {
    const float* input  = (const float*)d_in[0];
    const float* weight = (const float*)d_in[1];
    const float* bias   = (const float*)d_in[2];
    const int*   grid3d = (const int*)  d_in[3];
    const float* rot    = (const float*)d_in[4];
    const float* coord  = (const float*)d_in[5];
    const int*   max_r  = (const int*)  d_in[6];
    float* out = (float*)d_out;

    const int P = in_sizes[5] / 2;        // 13041
    const int B = in_sizes[4] / 9;        // 256
    const int W = in_sizes[1] / 16;       // weight_count

    const size_t wpk_bytes  = (size_t)W * 32;
    const size_t garr_bytes = (size_t)NCELL * 8;
    const size_t need_full  = wpk_bytes + garr_bytes;   // ~53 MB
    const size_t need_bf    = (size_t)W * 36;           // ~39 MB

    dim3 block(256, 1, 1);

    if (ws_size >= need_full) {
        unsigned* wpk = (unsigned*)d_ws;
        int2* garr = (int2*)((char*)d_ws + wpk_bytes);
        const int nw4 = W * 4;
        const int nbw = (nw4 + 255) / 256;
        const int nbg = (NCELL + 255) / 256;
        pack_all<<<nbw + nbg, block, 0, stream>>>(
            (const float4*)weight, (uint2*)wpk, nw4, nbw,
            grid3d, bias, garr, NCELL);
        dim3 grid(NBX2 * B, 1, 1);
        svr_h16<<<grid, block, 0, stream>>>(input, wpk, garr, rot, coord,
                                            max_r, out, P);
    } else if (ws_size >= need_bf) {
        unsigned* wpk = (unsigned*)d_ws;
        unsigned* bpk = wpk + (size_t)W * 8;
        const int nw = W * 4;
        pack_w<<<(nw + 255) / 256, block, 0, stream>>>(
            (const float4*)weight, (uint2*)wpk, nw);
        pack_b<<<(W + 255) / 256, block, 0, stream>>>(bias, bpk, W);
        dim3 grid(NBX * B, 1, 1);
        svr_bf16<<<grid, block, 0, stream>>>(input, wpk, bpk, grid3d, rot,
                                             coord, max_r, out, P);
    } else {
        dim3 grid(NBX * B, 1, 1);
        svr_fp32<<<grid, block, 0, stream>>>(input, weight, bias, grid3d, rot,
                                             coord, max_r, out, P);
    }
}

// Round 7
// 245.117 us; speedup vs baseline: 1.0810x; 1.0810x over previous
//
#include <hip/hip_runtime.h>

#define BZ    167              // grid3d_index dims 0/1 (SIZE + 2*MARGIN)
#define BZ2   83               // BZ/2
#define NX    84               // BZ/2 + 1  (last axis)
#define NCELL (BZ * BZ * NX)   // 2,342,676 cells
#define NBX   51               // ceil(13041/256) blocks/batch (fallback tiers)

// ---- bf16 helpers (round-to-nearest-even pack, free unpack) ----
static __device__ __forceinline__ unsigned f2bf(float f) {
    unsigned u = __float_as_uint(f);
    return (u + 0x7FFFu + ((u >> 16) & 1u)) >> 16;
}
static __device__ __forceinline__ float bf_lo(unsigned u) {
    return __uint_as_float(u << 16);
}
static __device__ __forceinline__ float bf_hi(unsigned u) {
    return __uint_as_float(u & 0xFFFF0000u);
}

// ---- fused pre-pass: pack weights fp32->bf16 (coalesced float4->uint2) AND
// build garr[cell] = (j, bias_bf16x2) in one dispatch ----
__global__ __launch_bounds__(256) void pack_all(
    const float4* __restrict__ wsrc, uint2* __restrict__ wdst, int nw4, int nbw,
    const int* __restrict__ grid, const float* __restrict__ bias,
    int2* __restrict__ garr, int ncell)
{
    if ((int)blockIdx.x < nbw) {
        const int i = blockIdx.x * 256 + threadIdx.x;
        if (i >= nw4) return;
        const float4 v = wsrc[i];
        wdst[i] = make_uint2(f2bf(v.x) | (f2bf(v.y) << 16),
                             f2bf(v.z) | (f2bf(v.w) << 16));
    } else {
        const int i = ((int)blockIdx.x - nbw) * 256 + threadIdx.x;
        if (i >= ncell) return;
        const int j = grid[i];
        unsigned bb = 0u;
        if (j >= 0)
            bb = f2bf(bias[2 * j]) | (f2bf(bias[2 * j + 1]) << 16);
        garr[i] = make_int2(j, (int)bb);
    }
}

// ========== main kernel: lane-paired half-records, 2 points/thread ==========
// Lane pair (2q,2q+1) computes TWO points (pA, pB = pA+128): even lane =
// input dims 0-3 + first 16B of each weight record, odd lane = dims 4-7 +
// second 16B. Two fully independent gather+math chains per thread give the
// scheduler 2x work per vmcnt-wait window and ~2x outstanding scatters
// (R6 lesson: single-chain version is exposed-latency bound at VALU=23%).
__global__ __launch_bounds__(256) void svr_half2(
    const float*    __restrict__ input,   // (B, 8)
    const unsigned* __restrict__ wpk,     // (W, 8) uints = 16 bf16
    const int2*     __restrict__ garr,    // (NCELL): (j, bias bf16x2)
    const float*    __restrict__ rot,     // (B, 3, 3)
    const float*    __restrict__ coord,   // (P, 2)
    const int*      __restrict__ max_r,
    float*          __restrict__ out,     // (B, P, 2)
    int P, int nbx)
{
    const int m    = blockIdx.x;
    const int xcd  = m & 7;                    // XCD-aware batch striping
    const int slot = m >> 3;
    const int b    = (slot / nbx) * 8 + xcd;
    const int tid  = threadIdx.x;
    const int half = tid & 1;
    const int qp   = tid >> 1;                 // pair index 0..127
    const int p0   = (slot % nbx) * 256;
    const int pA   = p0 + qp;                  // always < P (nbx=ceil(P/256))
    const int pB   = p0 + 128 + qp;
    const bool flagB = (pB < P);
    const int pBc  = flagB ? pB : (P - 1);

    const int mr = min(max_r[0], (BZ - 6) / 2);
    const float mr2 = (float)(mr * mr);

    const float2 xyA = *(const float2*)(coord + 2 * pA);
    const float2 xyB = *(const float2*)(coord + 2 * pBc);
    const bool validA = (xyA.x * xyA.x + xyA.y * xyA.y) <= mr2;
    const bool validB = flagB && ((xyB.x * xyB.x + xyB.y * xyB.y) <= mr2);

    float* oA = out + (((size_t)b * P + pA) * 2 + half);
    float* oB = out + (((size_t)b * P + pBc) * 2 + half);

    // pair-coherent early-out: both lanes of a pair share points, so no
    // divergence across the later shfl_xor
    if (!validA && !validB) {
        *oA = 0.f;
        if (flagB) *oB = 0.f;
        return;
    }

    const float* R = rot + b * 9;
    const float R0 = R[0], R1 = R[1], R3 = R[3], R4 = R[4], R6 = R[6], R7 = R[7];

    // ---- point A geometry (invalid -> c = 0, exactly like the reference) ----
    float cxA = fmaf(R1, xyA.y, R0 * xyA.x);
    float cyA = fmaf(R4, xyA.y, R3 * xyA.x);
    float czA = fmaf(R7, xyA.y, R6 * xyA.x);
    float sgnA = 1.f;
    if (cxA < 0.f) { cxA = -cxA; cyA = -cyA; czA = -czA; sgnA = -1.f; }
    if (!validA) { cxA = 0.f; cyA = 0.f; czA = 0.f; }
    const float fxA = floorf(cxA), fyA = floorf(cyA), fzA = floorf(czA);
    const float txA = cxA - fxA, tyA = cyA - fyA, tzA = czA - fzA;
    const int ixA = (int)fxA, iyA = (int)fyA + BZ2, izA = (int)fzA + BZ2;

    // ---- point B geometry ----
    float cxB = fmaf(R1, xyB.y, R0 * xyB.x);
    float cyB = fmaf(R4, xyB.y, R3 * xyB.x);
    float czB = fmaf(R7, xyB.y, R6 * xyB.x);
    float sgnB = 1.f;
    if (cxB < 0.f) { cxB = -cxB; cyB = -cyB; czB = -czB; sgnB = -1.f; }
    if (!validB) { cxB = 0.f; cyB = 0.f; czB = 0.f; }
    const float fxB = floorf(cxB), fyB = floorf(cyB), fzB = floorf(czB);
    const float txB = cxB - fxB, tyB = cyB - fyB, tzB = czB - fzB;
    const int ixB = (int)fxB, iyB = (int)fyB + BZ2, izB = (int)fzB + BZ2;

    // this lane's half of input[b] (block-uniform)
    const float4 ih = *(const float4*)(input + b * 8 + half * 4);

    // ---- clustered (j,bias) loads for BOTH points: 16 loads in flight ----
    int2 GA[8], GB[8];
    #pragma unroll
    for (int dz = 0; dz < 2; ++dz) {
        #pragma unroll
        for (int dy = 0; dy < 2; ++dy) {
            const int c = dz * 4 + dy * 2;
            const int baseA = ((izA + dz) * BZ + (iyA + dy)) * NX + ixA;
            const int baseB = ((izB + dz) * BZ + (iyB + dy)) * NX + ixB;
            GA[c + 0] = garr[baseA + 0];
            GA[c + 1] = garr[baseA + 1];
            GB[c + 0] = garr[baseB + 0];
            GB[c + 1] = garr[baseB + 1];
        }
    }

    int jjA[8], jjB[8];
    float wcA[8], wcB[8];
    unsigned bbA[8], bbB[8];
    {
        const float ax0 = 1.f - txA, ay0 = 1.f - tyA, az0 = 1.f - tzA;
        const float bx0 = 1.f - txB, by0 = 1.f - tyB, bz0 = 1.f - tzB;
        #pragma unroll
        for (int c = 0; c < 8; ++c) {
            const int dx = c & 1, dy = (c >> 1) & 1, dz = c >> 2;
            const float wA = (dx ? txA : ax0) * (dy ? tyA : ay0) * (dz ? tzA : az0);
            const float wB = (dx ? txB : bx0) * (dy ? tyB : by0) * (dz ? tzB : bz0);
            wcA[c] = (GA[c].x >= 0 && validA) ? wA : 0.f;
            wcB[c] = (GB[c].x >= 0 && validB) ? wB : 0.f;
            jjA[c] = max(GA[c].x, 0);
            jjB[c] = max(GB[c].x, 0);
            bbA[c] = (unsigned)GA[c].y;
            bbB[c] = (unsigned)GB[c].y;
        }
    }

    // ---- 16 scatter loads (1 per corner per point), all addresses ready ----
    uint4 UA[8], UB[8];
    #pragma unroll
    for (int c = 0; c < 8; ++c) {
        UA[c] = *(const uint4*)(wpk + (size_t)jjA[c] * 8 + half * 4);
        UB[c] = *(const uint4*)(wpk + (size_t)jjB[c] * 8 + half * 4);
    }

    // ---- two independent accumulation chains, interleaved per corner ----
    float a0 = 0.f, a1 = 0.f, b0 = 0.f, b1 = 0.f;
    #pragma unroll
    for (int c = 0; c < 8; ++c) {
        float v0 = half ? 0.f : bf_lo(bbA[c]);
        float v1 = half ? 0.f : bf_hi(bbA[c]);
        v0 = fmaf(ih.x, bf_lo(UA[c].x), v0); v1 = fmaf(ih.x, bf_hi(UA[c].x), v1);
        v0 = fmaf(ih.y, bf_lo(UA[c].y), v0); v1 = fmaf(ih.y, bf_hi(UA[c].y), v1);
        v0 = fmaf(ih.z, bf_lo(UA[c].z), v0); v1 = fmaf(ih.z, bf_hi(UA[c].z), v1);
        v0 = fmaf(ih.w, bf_lo(UA[c].w), v0); v1 = fmaf(ih.w, bf_hi(UA[c].w), v1);
        a0 = fmaf(wcA[c], v0, a0);
        a1 = fmaf(wcA[c], v1, a1);

        float u0 = half ? 0.f : bf_lo(bbB[c]);
        float u1 = half ? 0.f : bf_hi(bbB[c]);
        u0 = fmaf(ih.x, bf_lo(UB[c].x), u0); u1 = fmaf(ih.x, bf_hi(UB[c].x), u1);
        u0 = fmaf(ih.y, bf_lo(UB[c].y), u0); u1 = fmaf(ih.y, bf_hi(UB[c].y), u1);
        u0 = fmaf(ih.z, bf_lo(UB[c].z), u0); u1 = fmaf(ih.z, bf_hi(UB[c].z), u1);
        u0 = fmaf(ih.w, bf_lo(UB[c].w), u0); u1 = fmaf(ih.w, bf_hi(UB[c].w), u1);
        b0 = fmaf(wcB[c], u0, b0);
        b1 = fmaf(wcB[c], u1, b1);
    }

    // combine half-dot partials within the lane pair
    const float tA0 = a0 + __shfl_xor(a0, 1);
    const float tA1 = (a1 + __shfl_xor(a1, 1)) * sgnA;
    const float tB0 = b0 + __shfl_xor(b0, 1);
    const float tB1 = (b1 + __shfl_xor(b1, 1)) * sgnB;

    const float rA = half ? tA1 : tA0;
    const float rB = half ? tB1 : tB0;
    *oA = validA ? rA : 0.f;
    if (flagB) *oB = validB ? rB : 0.f;
}

// ============ fallback tier 2: bf16 weights + separate bias ==================
__global__ __launch_bounds__(256) void pack_w(
    const float4* __restrict__ src, uint2* __restrict__ dst, int n)
{
    const int i = blockIdx.x * 256 + threadIdx.x;
    if (i >= n) return;
    const float4 v = src[i];
    dst[i] = make_uint2(f2bf(v.x) | (f2bf(v.y) << 16),
                        f2bf(v.z) | (f2bf(v.w) << 16));
}
__global__ __launch_bounds__(256) void pack_b(
    const float* __restrict__ bias, unsigned* __restrict__ bpk, int W)
{
    const int j = blockIdx.x * 256 + threadIdx.x;
    if (j >= W) return;
    bpk[j] = f2bf(bias[2 * j]) | (f2bf(bias[2 * j + 1]) << 16);
}

__global__ __launch_bounds__(256) void svr_bf16(
    const float* __restrict__ input, const unsigned* __restrict__ wpk,
    const unsigned* __restrict__ bpk, const int* __restrict__ grid3d,
    const float* __restrict__ rot, const float* __restrict__ coord,
    const int* __restrict__ max_r, float* __restrict__ out, int P)
{
    const int m    = blockIdx.x;
    const int xcd  = m & 7;
    const int slot = m >> 3;
    const int b    = (slot / NBX) * 8 + xcd;
    const int p    = (slot % NBX) * 256 + threadIdx.x;
    if (p >= P) return;

    const float x = coord[2 * p + 0];
    const float y = coord[2 * p + 1];
    const int mr = min(max_r[0], (BZ - 6) / 2);
    const bool valid = (x * x + y * y) <= (float)(mr * mr);
    float2* o = (float2*)(out + ((size_t)b * P + p) * 2);
    if (!valid) { *o = make_float2(0.f, 0.f); return; }

    const float* R = rot + b * 9;
    float cx = fmaf(R[1], y, R[0] * x);
    float cy = fmaf(R[4], y, R[3] * x);
    float cz = fmaf(R[7], y, R[6] * x);
    float sgn = 1.f;
    if (cx < 0.f) { cx = -cx; cy = -cy; cz = -cz; sgn = -1.f; }
    const float fx = floorf(cx), fy = floorf(cy), fz = floorf(cz);
    const float tx = cx - fx, ty = cy - fy, tz = cz - fz;
    const int ix = (int)fx, iy = (int)fy + BZ2, iz = (int)fz + BZ2;

    const float* ib = input + b * 8;
    const float in0 = ib[0], in1 = ib[1], in2 = ib[2], in3 = ib[3];
    const float in4 = ib[4], in5 = ib[5], in6 = ib[6], in7 = ib[7];

    int jj[8]; float wc[8];
    const float wx0 = 1.f - tx, wy0 = 1.f - ty, wz0 = 1.f - tz;
    #pragma unroll
    for (int dz = 0; dz < 2; ++dz)
        #pragma unroll
        for (int dy = 0; dy < 2; ++dy) {
            const int base = ((iz + dz) * BZ + (iy + dy)) * NX + ix;
            #pragma unroll
            for (int dx = 0; dx < 2; ++dx) {
                const int c = dz * 4 + dy * 2 + dx;
                const int j = grid3d[base + dx];
                const float w = (dx ? tx : wx0) * (dy ? ty : wy0) * (dz ? tz : wz0);
                wc[c] = (j >= 0) ? w : 0.f;
                jj[c] = max(j, 0);
            }
        }

    uint4 U0[8], U1[8]; unsigned BB[8];
    #pragma unroll
    for (int c = 0; c < 8; ++c) {
        const uint4* wp = (const uint4*)(wpk + (size_t)jj[c] * 8);
        U0[c] = wp[0]; U1[c] = wp[1]; BB[c] = bpk[jj[c]];
    }

    float acc0 = 0.f, acc1 = 0.f;
    #pragma unroll
    for (int c = 0; c < 8; ++c) {
        const float w = wc[c];
        float v0 = bf_lo(BB[c]), v1 = bf_hi(BB[c]);
        v0 = fmaf(in0, bf_lo(U0[c].x), v0); v1 = fmaf(in0, bf_hi(U0[c].x), v1);
        v0 = fmaf(in1, bf_lo(U0[c].y), v0); v1 = fmaf(in1, bf_hi(U0[c].y), v1);
        v0 = fmaf(in2, bf_lo(U0[c].z), v0); v1 = fmaf(in2, bf_hi(U0[c].z), v1);
        v0 = fmaf(in3, bf_lo(U0[c].w), v0); v1 = fmaf(in3, bf_hi(U0[c].w), v1);
        v0 = fmaf(in4, bf_lo(U1[c].x), v0); v1 = fmaf(in4, bf_hi(U1[c].x), v1);
        v0 = fmaf(in5, bf_lo(U1[c].y), v0); v1 = fmaf(in5, bf_hi(U1[c].y), v1);
        v0 = fmaf(in6, bf_lo(U1[c].z), v0); v1 = fmaf(in6, bf_hi(U1[c].z), v1);
        v0 = fmaf(in7, bf_lo(U1[c].w), v0); v1 = fmaf(in7, bf_hi(U1[c].w), v1);
        acc0 = fmaf(w, v0, acc0);
        acc1 = fmaf(w, v1, acc1);
    }
    *o = make_float2(acc0, acc1 * sgn);
}

// ============ fallback tier 3: direct fp32 (no workspace needed) =============
__global__ __launch_bounds__(256) void svr_fp32(
    const float* __restrict__ input, const float* __restrict__ weight,
    const float* __restrict__ bias, const int* __restrict__ grid3d,
    const float* __restrict__ rot, const float* __restrict__ coord,
    const int* __restrict__ max_r, float* __restrict__ out, int P)
{
    const int m    = blockIdx.x;
    const int xcd  = m & 7;
    const int slot = m >> 3;
    const int b    = (slot / NBX) * 8 + xcd;
    const int p    = (slot % NBX) * 256 + threadIdx.x;
    if (p >= P) return;

    const float x = coord[2 * p + 0];
    const float y = coord[2 * p + 1];
    const int mr = min(max_r[0], (BZ - 6) / 2);
    const bool valid = (x * x + y * y) <= (float)(mr * mr);
    float2* o = (float2*)(out + ((size_t)b * P + p) * 2);
    if (!valid) { *o = make_float2(0.f, 0.f); return; }

    const float* R = rot + b * 9;
    float cx = fmaf(R[1], y, R[0] * x);
    float cy = fmaf(R[4], y, R[3] * x);
    float cz = fmaf(R[7], y, R[6] * x);
    float sgn = 1.f;
    if (cx < 0.f) { cx = -cx; cy = -cy; cz = -cz; sgn = -1.f; }
    const float fx = floorf(cx), fy = floorf(cy), fz = floorf(cz);
    const float tx = cx - fx, ty = cy - fy, tz = cz - fz;
    const int ix = (int)fx, iy = (int)fy + BZ2, iz = (int)fz + BZ2;

    const float* ib = input + b * 8;
    const float in0 = ib[0], in1 = ib[1], in2 = ib[2], in3 = ib[3];
    const float in4 = ib[4], in5 = ib[5], in6 = ib[6], in7 = ib[7];

    int jj[8]; float wc[8];
    const float wx0 = 1.f - tx, wy0 = 1.f - ty, wz0 = 1.f - tz;
    #pragma unroll
    for (int dz = 0; dz < 2; ++dz)
        #pragma unroll
        for (int dy = 0; dy < 2; ++dy) {
            const int base = ((iz + dz) * BZ + (iy + dy)) * NX + ix;
            #pragma unroll
            for (int dx = 0; dx < 2; ++dx) {
                const int c = dz * 4 + dy * 2 + dx;
                const int j = grid3d[base + dx];
                const float w = (dx ? tx : wx0) * (dy ? ty : wy0) * (dz ? tz : wz0);
                wc[c] = (j >= 0) ? w : 0.f;
                jj[c] = max(j, 0);
            }
        }

    float acc0 = 0.f, acc1 = 0.f;
    #pragma unroll
    for (int c = 0; c < 8; ++c) {
        const size_t j = (size_t)jj[c];
        const float4* wp = (const float4*)(weight + j * 16);
        const float4 W0 = wp[0], W1 = wp[1], W2 = wp[2], W3 = wp[3];
        const float2 bb = *(const float2*)(bias + j * 2);
        const float w = wc[c];
        float v0 = bb.x, v1 = bb.y;
        v0 = fmaf(in0, W0.x, v0); v1 = fmaf(in0, W0.y, v1);
        v0 = fmaf(in1, W0.z, v0); v1 = fmaf(in1, W0.w, v1);
        v0 = fmaf(in2, W1.x, v0); v1 = fmaf(in2, W1.y, v1);
        v0 = fmaf(in3, W1.z, v0); v1 = fmaf(in3, W1.w, v1);
        v0 = fmaf(in4, W2.x, v0); v1 = fmaf(in4, W2.y, v1);
        v0 = fmaf(in5, W2.z, v0); v1 = fmaf(in5, W2.w, v1);
        v0 = fmaf(in6, W3.x, v0); v1 = fmaf(in6, W3.y, v1);
        v0 = fmaf(in7, W3.z, v0); v1 = fmaf(in7, W3.w, v1);
        acc0 = fmaf(w, v0, acc0);
        acc1 = fmaf(w, v1, acc1);
    }
    *o = make_float2(acc0, acc1 * sgn);
}

extern "C" void kernel_launch(void* const* d_in, const int* in_sizes, int n_in,
                              void* d_out, int out_size, void* d_ws, size_t ws_size,
                              hipStream_t stream) {
    const float* input  = (const float*)d_in[0];
    const float* weight = (const float*)d_in[1];
    const float* bias   = (const float*)d_in[2];
    const int*   grid3d = (const int*)  d_in[3];
    const float* rot    = (const float*)d_in[4];
    const float* coord  = (const float*)d_in[5];
    const int*   max_r  = (const int*)  d_in[6];
    float* out = (float*)d_out;

    const int P = in_sizes[5] / 2;        // 13041
    const int B = in_sizes[4] / 9;        // 256
    const int W = in_sizes[1] / 16;       // weight_count

    const size_t wpk_bytes  = (size_t)W * 32;
    const size_t garr_bytes = (size_t)NCELL * 8;
    const size_t need_full  = wpk_bytes + garr_bytes;   // ~53 MB
    const size_t need_bf    = (size_t)W * 36;           // ~39 MB

    dim3 block(256, 1, 1);

    if (ws_size >= need_full) {
        unsigned* wpk = (unsigned*)d_ws;
        int2* garr = (int2*)((char*)d_ws + wpk_bytes);
        const int nw4 = W * 4;
        const int nbw = (nw4 + 255) / 256;
        const int nbg = (NCELL + 255) / 256;
        pack_all<<<nbw + nbg, block, 0, stream>>>(
            (const float4*)weight, (uint2*)wpk, nw4, nbw,
            grid3d, bias, garr, NCELL);
        const int nbx = (P + 255) / 256;  // 256 points per block (2/thread-pair)
        dim3 grid(nbx * B, 1, 1);
        svr_half2<<<grid, block, 0, stream>>>(input, wpk, garr, rot, coord,
                                              max_r, out, P, nbx);
    } else if (ws_size >= need_bf) {
        unsigned* wpk = (unsigned*)d_ws;
        unsigned* bpk = wpk + (size_t)W * 8;
        const int nw = W * 4;
        pack_w<<<(nw + 255) / 256, block, 0, stream>>>(
            (const float4*)weight, (uint2*)wpk, nw);
        pack_b<<<(W + 255) / 256, block, 0, stream>>>(bias, bpk, W);
        dim3 grid(NBX * B, 1, 1);
        svr_bf16<<<grid, block, 0, stream>>>(input, wpk, bpk, grid3d, rot,
                                             coord, max_r, out, P);
    } else {
        dim3 grid(NBX * B, 1, 1);
        svr_fp32<<<grid, block, 0, stream>>>(input, weight, bias, grid3d, rot,
                                             coord, max_r, out, P);
    }
}

// Round 8
// 236.496 us; speedup vs baseline: 1.1204x; 1.0365x over previous
//
#include <hip/hip_runtime.h>

#define BZ    167              // grid3d_index dims 0/1 (SIZE + 2*MARGIN)
#define BZ2   83               // BZ/2
#define NX    84               // BZ/2 + 1  (last axis)
#define NCELL (BZ * BZ * NX)   // 2,342,676 cells
#define NBX   51               // ceil(13041/256) blocks/batch (fallback tiers)
#define NBX2  102              // ceil(13041/128) blocks/batch (half-lane kernel)

// ---- bf16 helpers (round-to-nearest-even pack, free unpack) ----
static __device__ __forceinline__ unsigned f2bf(float f) {
    unsigned u = __float_as_uint(f);
    return (u + 0x7FFFu + ((u >> 16) & 1u)) >> 16;
}
static __device__ __forceinline__ float bf_lo(unsigned u) {
    return __uint_as_float(u << 16);
}
static __device__ __forceinline__ float bf_hi(unsigned u) {
    return __uint_as_float(u & 0xFFFF0000u);
}

// ---- fused pre-pass: pack weights fp32->bf16 (coalesced float4->uint2) AND
// build garr[cell] = (j, bias_bf16x2) in one dispatch ----
__global__ __launch_bounds__(256) void pack_all(
    const float4* __restrict__ wsrc, uint2* __restrict__ wdst, int nw4, int nbw,
    const int* __restrict__ grid, const float* __restrict__ bias,
    int2* __restrict__ garr, int ncell)
{
    if ((int)blockIdx.x < nbw) {
        const int i = blockIdx.x * 256 + threadIdx.x;
        if (i >= nw4) return;
        const float4 v = wsrc[i];
        wdst[i] = make_uint2(f2bf(v.x) | (f2bf(v.y) << 16),
                             f2bf(v.z) | (f2bf(v.w) << 16));
    } else {
        const int i = ((int)blockIdx.x - nbw) * 256 + threadIdx.x;
        if (i >= ncell) return;
        const int j = grid[i];
        unsigned bb = 0u;
        if (j >= 0)
            bb = f2bf(bias[2 * j]) | (f2bf(bias[2 * j + 1]) << 16);
        garr[i] = make_int2(j, (int)bb);
    }
}

// ============== main kernel: lane-paired half-record gathers =================
// R5 structure (best so far: 102 us) with __launch_bounds__(256, 4):
// min 4 waves/EU = 16 waves/CU -> VGPR budget 128, enough for the compiler to
// keep all 8 record loads + 8 garr loads in flight simultaneously instead of
// live-range-splitting at the default 64-VGPR cap (R5 showed VGPR=36: loads
// were being sliced). Concurrency = waves/CU x outstanding/wave is the
// binding constraint (R6/R7 evidence); this raises the second factor ~2x
// while keeping 16 waves/CU.
__global__ __launch_bounds__(256, 4) void svr_half(
    const float*    __restrict__ input,   // (B, 8)
    const unsigned* __restrict__ wpk,     // (W, 8) uints = 16 bf16
    const int2*     __restrict__ garr,    // (NCELL): (j, bias bf16x2)
    const float*    __restrict__ rot,     // (B, 3, 3)
    const float*    __restrict__ coord,   // (P, 2)
    const int*      __restrict__ max_r,
    float*          __restrict__ out,     // (B, P, 2)
    int P)
{
    const int m    = blockIdx.x;
    const int xcd  = m & 7;                    // XCD-aware batch striping
    const int slot = m >> 3;
    const int b    = (slot / NBX2) * 8 + xcd;
    const int lane = threadIdx.x;
    const int half = lane & 1;
    const int p    = (slot % NBX2) * 128 + (lane >> 1);
    if (p >= P) return;

    const float2 xy = *(const float2*)(coord + 2 * p);
    const float x = xy.x, y = xy.y;

    const int mr = min(max_r[0], (BZ - 6) / 2);
    const bool valid = (x * x + y * y) <= (float)(mr * mr);

    float* o = out + (((size_t)b * P + p) * 2 + half);   // 4B/lane, coalesced
    if (!valid) {
        *o = 0.f;
        return;
    }

    const float* R = rot + b * 9;
    float cx = fmaf(R[1], y, R[0] * x);
    float cy = fmaf(R[4], y, R[3] * x);
    float cz = fmaf(R[7], y, R[6] * x);

    float sgn = 1.f;
    if (cx < 0.f) { cx = -cx; cy = -cy; cz = -cz; sgn = -1.f; }

    const float fx = floorf(cx), fy = floorf(cy), fz = floorf(cz);
    const float tx = cx - fx, ty = cy - fy, tz = cz - fz;
    const int ix = (int)fx;
    const int iy = (int)fy + BZ2;
    const int iz = (int)fz + BZ2;

    // this lane's half of input[b]: dims 4*half .. 4*half+3 (16B aligned)
    const float4 ih = *(const float4*)(input + b * 8 + half * 4);

    // clustered (j,bias) loads — lane pairs share addresses (coalesce), few
    // lines per instruction; all 8 issued before any use
    int2 G[8];
    #pragma unroll
    for (int dz = 0; dz < 2; ++dz) {
        #pragma unroll
        for (int dy = 0; dy < 2; ++dy) {
            const int base = ((iz + dz) * BZ + (iy + dy)) * NX + ix;
            const int c = dz * 4 + dy * 2;
            G[c + 0] = garr[base + 0];
            G[c + 1] = garr[base + 1];
        }
    }

    int   jj[8];
    float wc[8];
    {
        const float wx0 = 1.f - tx, wy0 = 1.f - ty, wz0 = 1.f - tz;
        #pragma unroll
        for (int c = 0; c < 8; ++c) {
            const int dx = c & 1, dy = (c >> 1) & 1, dz = c >> 2;
            const float w = (dx ? tx : wx0) * (dy ? ty : wy0) * (dz ? tz : wz0);
            const int j = G[c].x;
            wc[c] = (j >= 0) ? w : 0.f;
            jj[c] = max(j, 0);
        }
    }

    // one 16B scatter load per corner per lane = full 32B record per lane
    // pair; with the 128-VGPR budget all 8 stay in flight (32 dest VGPRs)
    uint4 U[8];
    #pragma unroll
    for (int c = 0; c < 8; ++c)
        U[c] = *(const uint4*)(wpk + (size_t)jj[c] * 8 + half * 4);

    float acc0 = 0.f, acc1 = 0.f;
    #pragma unroll
    for (int c = 0; c < 8; ++c) {
        const float w = wc[c];
        const unsigned bb = (unsigned)G[c].y;
        // bias contributes once per point: even lane only
        float v0 = half ? 0.f : bf_lo(bb);
        float v1 = half ? 0.f : bf_hi(bb);
        v0 = fmaf(ih.x, bf_lo(U[c].x), v0); v1 = fmaf(ih.x, bf_hi(U[c].x), v1);
        v0 = fmaf(ih.y, bf_lo(U[c].y), v0); v1 = fmaf(ih.y, bf_hi(U[c].y), v1);
        v0 = fmaf(ih.z, bf_lo(U[c].z), v0); v1 = fmaf(ih.z, bf_hi(U[c].z), v1);
        v0 = fmaf(ih.w, bf_lo(U[c].w), v0); v1 = fmaf(ih.w, bf_hi(U[c].w), v1);
        acc0 = fmaf(w, v0, acc0);
        acc1 = fmaf(w, v1, acc1);
    }

    // combine the two half-dot partials within the lane pair
    const float t0 = acc0 + __shfl_xor(acc0, 1);
    const float t1 = (acc1 + __shfl_xor(acc1, 1)) * sgn;
    *o = half ? t1 : t0;
}

// ============ fallback tier 2: bf16 weights + separate bias ==================
__global__ __launch_bounds__(256) void pack_w(
    const float4* __restrict__ src, uint2* __restrict__ dst, int n)
{
    const int i = blockIdx.x * 256 + threadIdx.x;
    if (i >= n) return;
    const float4 v = src[i];
    dst[i] = make_uint2(f2bf(v.x) | (f2bf(v.y) << 16),
                        f2bf(v.z) | (f2bf(v.w) << 16));
}
__global__ __launch_bounds__(256) void pack_b(
    const float* __restrict__ bias, unsigned* __restrict__ bpk, int W)
{
    const int j = blockIdx.x * 256 + threadIdx.x;
    if (j >= W) return;
    bpk[j] = f2bf(bias[2 * j]) | (f2bf(bias[2 * j + 1]) << 16);
}

__global__ __launch_bounds__(256) void svr_bf16(
    const float* __restrict__ input, const unsigned* __restrict__ wpk,
    const unsigned* __restrict__ bpk, const int* __restrict__ grid3d,
    const float* __restrict__ rot, const float* __restrict__ coord,
    const int* __restrict__ max_r, float* __restrict__ out, int P)
{
    const int m    = blockIdx.x;
    const int xcd  = m & 7;
    const int slot = m >> 3;
    const int b    = (slot / NBX) * 8 + xcd;
    const int p    = (slot % NBX) * 256 + threadIdx.x;
    if (p >= P) return;

    const float x = coord[2 * p + 0];
    const float y = coord[2 * p + 1];
    const int mr = min(max_r[0], (BZ - 6) / 2);
    const bool valid = (x * x + y * y) <= (float)(mr * mr);
    float2* o = (float2*)(out + ((size_t)b * P + p) * 2);
    if (!valid) { *o = make_float2(0.f, 0.f); return; }

    const float* R = rot + b * 9;
    float cx = fmaf(R[1], y, R[0] * x);
    float cy = fmaf(R[4], y, R[3] * x);
    float cz = fmaf(R[7], y, R[6] * x);
    float sgn = 1.f;
    if (cx < 0.f) { cx = -cx; cy = -cy; cz = -cz; sgn = -1.f; }
    const float fx = floorf(cx), fy = floorf(cy), fz = floorf(cz);
    const float tx = cx - fx, ty = cy - fy, tz = cz - fz;
    const int ix = (int)fx, iy = (int)fy + BZ2, iz = (int)fz + BZ2;

    const float* ib = input + b * 8;
    const float in0 = ib[0], in1 = ib[1], in2 = ib[2], in3 = ib[3];
    const float in4 = ib[4], in5 = ib[5], in6 = ib[6], in7 = ib[7];

    int jj[8]; float wc[8];
    const float wx0 = 1.f - tx, wy0 = 1.f - ty, wz0 = 1.f - tz;
    #pragma unroll
    for (int dz = 0; dz < 2; ++dz)
        #pragma unroll
        for (int dy = 0; dy < 2; ++dy) {
            const int base = ((iz + dz) * BZ + (iy + dy)) * NX + ix;
            #pragma unroll
            for (int dx = 0; dx < 2; ++dx) {
                const int c = dz * 4 + dy * 2 + dx;
                const int j = grid3d[base + dx];
                const float w = (dx ? tx : wx0) * (dy ? ty : wy0) * (dz ? tz : wz0);
                wc[c] = (j >= 0) ? w : 0.f;
                jj[c] = max(j, 0);
            }
        }

    uint4 U0[8], U1[8]; unsigned BB[8];
    #pragma unroll
    for (int c = 0; c < 8; ++c) {
        const uint4* wp = (const uint4*)(wpk + (size_t)jj[c] * 8);
        U0[c] = wp[0]; U1[c] = wp[1]; BB[c] = bpk[jj[c]];
    }

    float acc0 = 0.f, acc1 = 0.f;
    #pragma unroll
    for (int c = 0; c < 8; ++c) {
        const float w = wc[c];
        float v0 = bf_lo(BB[c]), v1 = bf_hi(BB[c]);
        v0 = fmaf(in0, bf_lo(U0[c].x), v0); v1 = fmaf(in0, bf_hi(U0[c].x), v1);
        v0 = fmaf(in1, bf_lo(U0[c].y), v0); v1 = fmaf(in1, bf_hi(U0[c].y), v1);
        v0 = fmaf(in2, bf_lo(U0[c].z), v0); v1 = fmaf(in2, bf_hi(U0[c].z), v1);
        v0 = fmaf(in3, bf_lo(U0[c].w), v0); v1 = fmaf(in3, bf_hi(U0[c].w), v1);
        v0 = fmaf(in4, bf_lo(U1[c].x), v0); v1 = fmaf(in4, bf_hi(U1[c].x), v1);
        v0 = fmaf(in5, bf_lo(U1[c].y), v0); v1 = fmaf(in5, bf_hi(U1[c].y), v1);
        v0 = fmaf(in6, bf_lo(U1[c].z), v0); v1 = fmaf(in6, bf_hi(U1[c].z), v1);
        v0 = fmaf(in7, bf_lo(U1[c].w), v0); v1 = fmaf(in7, bf_hi(U1[c].w), v1);
        acc0 = fmaf(w, v0, acc0);
        acc1 = fmaf(w, v1, acc1);
    }
    *o = make_float2(acc0, acc1 * sgn);
}

// ============ fallback tier 3: direct fp32 (no workspace needed) =============
__global__ __launch_bounds__(256) void svr_fp32(
    const float* __restrict__ input, const float* __restrict__ weight,
    const float* __restrict__ bias, const int* __restrict__ grid3d,
    const float* __restrict__ rot, const float* __restrict__ coord,
    const int* __restrict__ max_r, float* __restrict__ out, int P)
{
    const int m    = blockIdx.x;
    const int xcd  = m & 7;
    const int slot = m >> 3;
    const int b    = (slot / NBX) * 8 + xcd;
    const int p    = (slot % NBX) * 256 + threadIdx.x;
    if (p >= P) return;

    const float x = coord[2 * p + 0];
    const float y = coord[2 * p + 1];
    const int mr = min(max_r[0], (BZ - 6) / 2);
    const bool valid = (x * x + y * y) <= (float)(mr * mr);
    float2* o = (float2*)(out + ((size_t)b * P + p) * 2);
    if (!valid) { *o = make_float2(0.f, 0.f); return; }

    const float* R = rot + b * 9;
    float cx = fmaf(R[1], y, R[0] * x);
    float cy = fmaf(R[4], y, R[3] * x);
    float cz = fmaf(R[7], y, R[6] * x);
    float sgn = 1.f;
    if (cx < 0.f) { cx = -cx; cy = -cy; cz = -cz; sgn = -1.f; }
    const float fx = floorf(cx), fy = floorf(cy), fz = floorf(cz);
    const float tx = cx - fx, ty = cy - fy, tz = cz - fz;
    const int ix = (int)fx, iy = (int)fy + BZ2, iz = (int)fz + BZ2;

    const float* ib = input + b * 8;
    const float in0 = ib[0], in1 = ib[1], in2 = ib[2], in3 = ib[3];
    const float in4 = ib[4], in5 = ib[5], in6 = ib[6], in7 = ib[7];

    int jj[8]; float wc[8];
    const float wx0 = 1.f - tx, wy0 = 1.f - ty, wz0 = 1.f - tz;
    #pragma unroll
    for (int dz = 0; dz < 2; ++dz)
        #pragma unroll
        for (int dy = 0; dy < 2; ++dy) {
            const int base = ((iz + dz) * BZ + (iy + dy)) * NX + ix;
            #pragma unroll
            for (int dx = 0; dx < 2; ++dx) {
                const int c = dz * 4 + dy * 2 + dx;
                const int j = grid3d[base + dx];
                const float w = (dx ? tx : wx0) * (dy ? ty : wy0) * (dz ? tz : wz0);
                wc[c] = (j >= 0) ? w : 0.f;
                jj[c] = max(j, 0);
            }
        }

    float acc0 = 0.f, acc1 = 0.f;
    #pragma unroll
    for (int c = 0; c < 8; ++c) {
        const size_t j = (size_t)jj[c];
        const float4* wp = (const float4*)(weight + j * 16);
        const float4 W0 = wp[0], W1 = wp[1], W2 = wp[2], W3 = wp[3];
        const float2 bb = *(const float2*)(bias + j * 2);
        const float w = wc[c];
        float v0 = bb.x, v1 = bb.y;
        v0 = fmaf(in0, W0.x, v0); v1 = fmaf(in0, W0.y, v1);
        v0 = fmaf(in1, W0.z, v0); v1 = fmaf(in1, W0.w, v1);
        v0 = fmaf(in2, W1.x, v0); v1 = fmaf(in2, W1.y, v1);
        v0 = fmaf(in3, W1.z, v0); v1 = fmaf(in3, W1.w, v1);
        v0 = fmaf(in4, W2.x, v0); v1 = fmaf(in4, W2.y, v1);
        v0 = fmaf(in5, W2.z, v0); v1 = fmaf(in5, W2.w, v1);
        v0 = fmaf(in6, W3.x, v0); v1 = fmaf(in6, W3.y, v1);
        v0 = fmaf(in7, W3.z, v0); v1 = fmaf(in7, W3.w, v1);
        acc0 = fmaf(w, v0, acc0);
        acc1 = fmaf(w, v1, acc1);
    }
    *o = make_float2(acc0, acc1 * sgn);
}

extern "C" void kernel_launch(void* const* d_in, const int* in_sizes, int n_in,
                              void* d_out, int out_size, void* d_ws, size_t ws_size,
                              hipStream_t stream) {
    const float* input  = (const float*)d_in[0];
    const float* weight = (const float*)d_in[1];
    const float* bias   = (const float*)d_in[2];
    const int*   grid3d = (const int*)  d_in[3];
    const float* rot    = (const float*)d_in[4];
    const float* coord  = (const float*)d_in[5];
    const int*   max_r  = (const int*)  d_in[6];
    float* out = (float*)d_out;

    const int P = in_sizes[5] / 2;        // 13041
    const int B = in_sizes[4] / 9;        // 256
    const int W = in_sizes[1] / 16;       // weight_count

    const size_t wpk_bytes  = (size_t)W * 32;
    const size_t garr_bytes = (size_t)NCELL * 8;
    const size_t need_full  = wpk_bytes + garr_bytes;   // ~53 MB
    const size_t need_bf    = (size_t)W * 36;           // ~39 MB

    dim3 block(256, 1, 1);

    if (ws_size >= need_full) {
        unsigned* wpk = (unsigned*)d_ws;
        int2* garr = (int2*)((char*)d_ws + wpk_bytes);
        const int nw4 = W * 4;
        const int nbw = (nw4 + 255) / 256;
        const int nbg = (NCELL + 255) / 256;
        pack_all<<<nbw + nbg, block, 0, stream>>>(
            (const float4*)weight, (uint2*)wpk, nw4, nbw,
            grid3d, bias, garr, NCELL);
        dim3 grid(NBX2 * B, 1, 1);
        svr_half<<<grid, block, 0, stream>>>(input, wpk, garr, rot, coord,
                                             max_r, out, P);
    } else if (ws_size >= need_bf) {
        unsigned* wpk = (unsigned*)d_ws;
        unsigned* bpk = wpk + (size_t)W * 8;
        const int nw = W * 4;
        pack_w<<<(nw + 255) / 256, block, 0, stream>>>(
            (const float4*)weight, (uint2*)wpk, nw);
        pack_b<<<(W + 255) / 256, block, 0, stream>>>(bias, bpk, W);
        dim3 grid(NBX * B, 1, 1);
        svr_bf16<<<grid, block, 0, stream>>>(input, wpk, bpk, grid3d, rot,
                                             coord, max_r, out, P);
    } else {
        dim3 grid(NBX * B, 1, 1);
        svr_fp32<<<grid, block, 0, stream>>>(input, weight, bias, grid3d, rot,
                                             coord, max_r, out, P);
    }
}